// Round 2
// baseline (223.078 us; speedup 1.0000x reference)
//
#include <hip/hip_runtime.h>
#include <math.h>

#define NT 365
#define NS 2048
#define NH 64
#define NG 128
#define NW 513      // nh*8+1
#define WSTR 520    // padded row stride for w buffer

__device__ __forceinline__ float sigmoidf_(float x) {
    return 1.0f / (1.0f + __expf(-x));
}

// ---------------- Kernel A: forcing transform (Ps, Pl, E, Ta) ----------------
__global__ __launch_bounds__(256) void forcing_kernel(const float* __restrict__ x,
                                                      float* __restrict__ f, int n) {
    int i = blockIdx.x * blockDim.x + threadIdx.x;
    if (i >= n) return;
    float4 v = ((const float4*)x)[i];
    float P = v.x, E = v.y, T1 = v.z, T2 = v.w;
    float Ta = 0.5f * (T1 + T2);
    float rP;
    if (T2 <= 0.0f)       rP = 0.0f;                 // mask0 wins (applied last in ref)
    else if (T1 >= 0.0f)  rP = 1.0f;
    else                  rP = 1.0f - acosf((T1 + T2) / (T2 - T1)) * (1.0f / 3.1415f);
    float Ps = (1.0f - rP) * P;
    float Pl = rP * P;
    ((float4*)f)[i] = make_float4(Ps, Pl, E, Ta);
}

// ---------------- Kernel B: w = xc @ W^T + b  -> [NS, NW] (stride WSTR) ------
// 64(s) x 64(j) tile per block, K=128 fully staged in LDS, 4x4 register block.
__global__ __launch_bounds__(256) void gemm_kernel(const float* __restrict__ xc,
                                                   const float* __restrict__ Wm,
                                                   const float* __restrict__ bv,
                                                   float* __restrict__ w) {
    __shared__ float xcs[64][132];  // +4 pad: breaks bank conflict on column reads
    __shared__ float Wsh[64][132];
    const int sTile = blockIdx.x * 64;   // 32 tiles
    const int jTile = blockIdx.y * 64;   // 9 tiles (last has 1 valid row)
    const int t = threadIdx.x;

    // cooperative load: 64 rows x 128 cols each = 2048 float4s per tile
    for (int i = 0; i < 8; i++) {
        int f4  = t + i * 256;
        int row = f4 >> 5;
        int c4  = (f4 & 31) * 4;
        float4 v = ((const float4*)(xc + (size_t)(sTile + row) * NG))[f4 & 31];
        xcs[row][c4] = v.x; xcs[row][c4 + 1] = v.y; xcs[row][c4 + 2] = v.z; xcs[row][c4 + 3] = v.w;
        int jr = jTile + row;
        float4 wv = make_float4(0.f, 0.f, 0.f, 0.f);
        if (jr < NW) wv = ((const float4*)(Wm + (size_t)jr * NG))[f4 & 31];
        Wsh[row][c4] = wv.x; Wsh[row][c4 + 1] = wv.y; Wsh[row][c4 + 2] = wv.z; Wsh[row][c4 + 3] = wv.w;
    }
    __syncthreads();

    const int tx = t & 15, ty = t >> 4;
    float acc[4][4] = {};
#pragma unroll 4
    for (int k = 0; k < 128; k++) {
        float a0 = xcs[ty][k], a1 = xcs[ty + 16][k], a2 = xcs[ty + 32][k], a3 = xcs[ty + 48][k];
        float b0 = Wsh[tx][k], b1 = Wsh[tx + 16][k], b2 = Wsh[tx + 32][k], b3 = Wsh[tx + 48][k];
        acc[0][0] += a0 * b0; acc[0][1] += a0 * b1; acc[0][2] += a0 * b2; acc[0][3] += a0 * b3;
        acc[1][0] += a1 * b0; acc[1][1] += a1 * b1; acc[1][2] += a1 * b2; acc[1][3] += a1 * b3;
        acc[2][0] += a2 * b0; acc[2][1] += a2 * b1; acc[2][2] += a2 * b2; acc[2][3] += a2 * b3;
        acc[3][0] += a3 * b0; acc[3][1] += a3 * b1; acc[3][2] += a3 * b2; acc[3][3] += a3 * b3;
    }
#pragma unroll
    for (int i = 0; i < 4; i++) {
        int s = sTile + ty + 16 * i;
#pragma unroll
        for (int j = 0; j < 4; j++) {
            int jj = jTile + tx + 16 * j;
            if (jj < NW) w[(size_t)s * WSTR + jj] = acc[i][j] + bv[jj];
        }
    }
}

// ---------------- Kernel C: sequential scan, one wave per site ----------------
// Forcing load for t+1 is prefetched before computing step t so the global
// load latency overlaps the serial VALU chain.
template <bool PRE>
__global__ __launch_bounds__(256) void scan_kernel(const float* __restrict__ fx,
                                                   const float* __restrict__ w,
                                                   float* __restrict__ Y) {
    const int wave = threadIdx.x >> 6;
    const int lane = threadIdx.x & 63;
    const int s = blockIdx.x * 4 + wave;
    const float* wr = w + (size_t)s * WSTR;

    // gate parameters (per lane = per hidden unit)
    float gm = __expf(wr[lane]) + 1.0f;            // w[:, 0:64]
    float ge = 2.0f * sigmoidf_(wr[64 + lane]);    // w[:, 64:128]
    float k0 = sigmoidf_(wr[192 + lane]);          // w[:, 192:256]
    float w4 = wr[256 + lane];                     // w[:, 256:320]
    float k1 = sigmoidf_(w4);
    float k2 = sigmoidf_(wr[320 + lane]);          // w[:, 320:384]
    float gl = __expf(wr[384 + lane]);             // w[:, 384:448]
    float kb = sigmoidf_(wr[448 + lane]) * 0.1f;   // w[:, 448:512]
    float wl = wr[512];                            // w[:, 512] (per-site scalar)
    float qb = fmaxf(wl, 0.0f) * (1.0f / (float)NH);
    float vi = sigmoidf_(wl);

    // softmax over the 64 lanes of w4 -> ga
    float m = w4;
#pragma unroll
    for (int off = 32; off; off >>= 1) m = fmaxf(m, __shfl_xor(m, off));
    float ex = __expf(w4 - m);
    float sum = ex;
#pragma unroll
    for (int off = 32; off; off >>= 1) sum += __shfl_xor(sum, off);
    float ga = ex / sum;

    float S0 = 0.f, H0 = 0.f, H1 = 0.f, H2 = 0.f;
    float4 v = ((const float4*)fx)[s];   // t = 0 forcing
    for (int t = 0; t < NT; t++) {
        float4 vn;
        if (t + 1 < NT) vn = ((const float4*)fx)[(t + 1) * NS + s];  // prefetch
        float Ps, Pl, E, Ta;
        if (PRE) {
            Ps = v.x; Pl = v.y; E = v.z; Ta = v.w;
        } else {
            float P = v.x; E = v.y;
            float T1 = v.z, T2 = v.w;
            Ta = 0.5f * (T1 + T2);
            float rP;
            if (T2 <= 0.0f)      rP = 0.0f;
            else if (T1 >= 0.0f) rP = 1.0f;
            else                 rP = 1.0f - acosf((T1 + T2) / (T2 - T1)) * (1.0f / 3.1415f);
            Ps = (1.0f - rP) * P;
            Pl = rP * P;
        }
        float S  = S0 + Ps;
        float Sm = fminf(S0, fmaxf(Ta * gm, 0.0f));       // uses OLD S0
        float G1 = fmaxf(H1 + Sm + Pl * vi - E * ge, 0.0f);
        float G0 = fmaxf(H0 + G1 - gl + Pl * (1.0f - vi), 0.0f);
        float Q0  = G0 * k0;
        float Q1a = fminf(G1, gl) * k1;
        float Q1  = Q1a * (1.0f - kb);
        float G2  = H2 + Q1a * kb;
        float Q2  = G2 * k2;
        float y = (Q0 + Q1 + Q2 + qb) * ga;
#pragma unroll
        for (int off = 32; off; off >>= 1) y += __shfl_xor(y, off);
        if (lane == 0) Y[(size_t)t * NS + s] = y;
        S0 = S - Sm;
        H0 = G0 - Q0;
        H1 = fminf(G1 - Q1a, gl);
        H2 = G2 - Q2;
        v = vn;
    }
}

extern "C" void kernel_launch(void* const* d_in, const int* in_sizes, int n_in,
                              void* d_out, int out_size, void* d_ws, size_t ws_size,
                              hipStream_t stream) {
    const float* x  = (const float*)d_in[0];   // [NT, NS, 4]
    const float* xc = (const float*)d_in[1];   // [NS, NG]
    const float* Wm = (const float*)d_in[2];   // [NW, NG]
    const float* bv = (const float*)d_in[3];   // [NW]
    float* out = (float*)d_out;                // [NT, NS] fp32

    float* wbuf = (float*)d_ws;                                 // NS*WSTR floats
    size_t wbytes = (size_t)NS * WSTR * sizeof(float);          // 4,259,840 B
    float* fbuf = (float*)((char*)d_ws + wbytes);               // NT*NS float4
    size_t need = wbytes + (size_t)NT * NS * 4 * sizeof(float); // ~16.2 MB

    gemm_kernel<<<dim3(32, 9), 256, 0, stream>>>(xc, Wm, bv, wbuf);

    if (ws_size >= need) {
        forcing_kernel<<<(NT * NS + 255) / 256, 256, 0, stream>>>(x, fbuf, NT * NS);
        scan_kernel<true><<<NS / 4, 256, 0, stream>>>(fbuf, wbuf, out);
    } else {
        scan_kernel<false><<<NS / 4, 256, 0, stream>>>(x, wbuf, out);
    }
}

// Round 3
// 163.787 us; speedup vs baseline: 1.3620x; 1.3620x over previous
//
#include <hip/hip_runtime.h>
#include <math.h>

#define NT 365
#define NS 2048
#define NH 64
#define NG 128
#define NW 513      // nh*8+1
#define WSTR 520    // padded row stride for w buffer

__device__ __forceinline__ float sigmoidf_(float x) {
    return 1.0f / (1.0f + __expf(-x));
}

// ---------------- Kernel A: forcing transform (Ps, Pl, E, relu(Ta)) ----------
__global__ __launch_bounds__(256) void forcing_kernel(const float* __restrict__ x,
                                                      float* __restrict__ f, int n) {
    int i = blockIdx.x * blockDim.x + threadIdx.x;
    if (i >= n) return;
    float4 v = ((const float4*)x)[i];
    float P = v.x, E = v.y, T1 = v.z, T2 = v.w;
    float Ta = 0.5f * (T1 + T2);
    float rP;
    if (T2 <= 0.0f)       rP = 0.0f;                 // mask0 wins (applied last in ref)
    else if (T1 >= 0.0f)  rP = 1.0f;
    else                  rP = 1.0f - acosf((T1 + T2) / (T2 - T1)) * (1.0f / 3.1415f);
    float Ps = (1.0f - rP) * P;
    float Pl = rP * P;
    ((float4*)f)[i] = make_float4(Ps, Pl, E, fmaxf(Ta, 0.0f));  // store relu(Ta)
}

// ---------------- Kernel B: w = xc @ W^T + b  -> [NS, NW] (stride WSTR) ------
// 64(s) x 64(j) tile, K=128 staged in LDS, 4x4 register block.
// j-tile 2 (cols 128..191) is never consumed by the scan -> skipped via remap.
__global__ __launch_bounds__(256) void gemm_kernel(const float* __restrict__ xc,
                                                   const float* __restrict__ Wm,
                                                   const float* __restrict__ bv,
                                                   float* __restrict__ w) {
    __shared__ float xcs[64][132];  // +4 pad: breaks bank conflict on column reads
    __shared__ float Wsh[64][132];
    const int sTile = blockIdx.x * 64;                       // 32 tiles
    const int by = blockIdx.y;
    const int jt = (by >= 2) ? by + 1 : by;                  // skip unused tile 2
    const int jTile = jt * 64;
    const int t = threadIdx.x;

    for (int i = 0; i < 8; i++) {
        int f4  = t + i * 256;
        int row = f4 >> 5;
        int c4  = (f4 & 31) * 4;
        float4 v = ((const float4*)(xc + (size_t)(sTile + row) * NG))[f4 & 31];
        xcs[row][c4] = v.x; xcs[row][c4 + 1] = v.y; xcs[row][c4 + 2] = v.z; xcs[row][c4 + 3] = v.w;
        int jr = jTile + row;
        float4 wv = make_float4(0.f, 0.f, 0.f, 0.f);
        if (jr < NW) wv = ((const float4*)(Wm + (size_t)jr * NG))[f4 & 31];
        Wsh[row][c4] = wv.x; Wsh[row][c4 + 1] = wv.y; Wsh[row][c4 + 2] = wv.z; Wsh[row][c4 + 3] = wv.w;
    }
    __syncthreads();

    const int tx = t & 15, ty = t >> 4;
    float acc[4][4] = {};
#pragma unroll 4
    for (int k = 0; k < 128; k++) {
        float a0 = xcs[ty][k], a1 = xcs[ty + 16][k], a2 = xcs[ty + 32][k], a3 = xcs[ty + 48][k];
        float b0 = Wsh[tx][k], b1 = Wsh[tx + 16][k], b2 = Wsh[tx + 32][k], b3 = Wsh[tx + 48][k];
        acc[0][0] += a0 * b0; acc[0][1] += a0 * b1; acc[0][2] += a0 * b2; acc[0][3] += a0 * b3;
        acc[1][0] += a1 * b0; acc[1][1] += a1 * b1; acc[1][2] += a1 * b2; acc[1][3] += a1 * b3;
        acc[2][0] += a2 * b0; acc[2][1] += a2 * b1; acc[2][2] += a2 * b2; acc[2][3] += a2 * b3;
        acc[3][0] += a3 * b0; acc[3][1] += a3 * b1; acc[3][2] += a3 * b2; acc[3][3] += a3 * b3;
    }
#pragma unroll
    for (int i = 0; i < 4; i++) {
        int s = sTile + ty + 16 * i;
#pragma unroll
        for (int j = 0; j < 4; j++) {
            int jj = jTile + tx + 16 * j;
            if (jj < NW) w[(size_t)s * WSTR + jj] = acc[i][j] + bv[jj];
        }
    }
}

// ---------------- Kernel C: sequential scan, one wave per site ----------------
// Time-batched by 8: the 64-lane y-reduction butterfly runs on 8 independent
// values (latency-hidden) instead of a serial 6-deep swizzle chain per step.
template <bool PRE>
__global__ __launch_bounds__(256) void scan_kernel(const float* __restrict__ fx,
                                                   const float* __restrict__ w,
                                                   float* __restrict__ Y) {
    const int wave = threadIdx.x >> 6;
    const int lane = threadIdx.x & 63;
    const int s = blockIdx.x * 4 + wave;
    const float* wr = w + (size_t)s * WSTR;

    // gate parameters (per lane = per hidden unit)
    float gm = __expf(wr[lane]) + 1.0f;            // w[:, 0:64]
    float ge = 2.0f * sigmoidf_(wr[64 + lane]);    // w[:, 64:128]
    float k0 = sigmoidf_(wr[192 + lane]);          // w[:, 192:256]
    float w4 = wr[256 + lane];                     // w[:, 256:320]
    float k1 = sigmoidf_(w4);
    float k2 = sigmoidf_(wr[320 + lane]);          // w[:, 320:384]
    float gl = __expf(wr[384 + lane]);             // w[:, 384:448]
    float kb = sigmoidf_(wr[448 + lane]) * 0.1f;   // w[:, 448:512]
    float wl = wr[512];                            // w[:, 512] (per-site scalar)
    float qb = fmaxf(wl, 0.0f) * (1.0f / (float)NH);
    float vi = sigmoidf_(wl);

    // softmax over the 64 lanes of w4 -> ga   (setup cost, once)
    float m = w4;
#pragma unroll
    for (int off = 32; off; off >>= 1) m = fmaxf(m, __shfl_xor(m, off));
    float ex = __expf(w4 - m);
    float sum = ex;
#pragma unroll
    for (int off = 32; off; off >>= 1) sum += __shfl_xor(sum, off);
    float ga = ex / sum;

    // folded output/state coefficients:
    //   y_h = ga*(Q0+Q1+Q2) = G0*c0 + min(G1,gl)*c1 + G2*c2 ;  Sum_h ga*qb = qb
    //   H0' = G0-Q0 = G0*(1-k0);  H2' = G2-Q2 = G2*(1-k2)
    float c0  = k0 * ga;
    float c1  = k1 * (1.0f - kb) * ga;
    float c2  = k2 * ga;
    float k0c = 1.0f - k0;
    float k2c = 1.0f - k2;

    float S0 = 0.f, H0 = 0.f, H1 = 0.f, H2 = 0.f;

    float4 vbuf[8];
#pragma unroll
    for (int b = 0; b < 8; b++) vbuf[b] = ((const float4*)fx)[b * NS + s];

    for (int t0 = 0; t0 < NT; t0 += 8) {
        float4 vc[8];
#pragma unroll
        for (int b = 0; b < 8; b++) vc[b] = vbuf[b];
        // prefetch next batch (loads overlap this batch's compute)
#pragma unroll
        for (int b = 0; b < 8; b++) {
            int tn = t0 + 8 + b;
            if (tn < NT) vbuf[b] = ((const float4*)fx)[tn * NS + s];
        }

        float yv[8];
#pragma unroll
        for (int b = 0; b < 8; b++) {
            float Ps, Pl, E, TaR;
            if (PRE) {
                Ps = vc[b].x; Pl = vc[b].y; E = vc[b].z; TaR = vc[b].w;
            } else {
                float P = vc[b].x; E = vc[b].y;
                float T1 = vc[b].z, T2 = vc[b].w;
                float Ta = 0.5f * (T1 + T2);
                float rP;
                if (T2 <= 0.0f)      rP = 0.0f;
                else if (T1 >= 0.0f) rP = 1.0f;
                else                 rP = 1.0f - acosf((T1 + T2) / (T2 - T1)) * (1.0f / 3.1415f);
                Ps = (1.0f - rP) * P;
                Pl = rP * P;
                TaR = fmaxf(Ta, 0.0f);
            }
            float S   = S0 + Ps;
            float Sm  = fminf(S0, gm * TaR);            // relu(Ta*gm) = gm*relu(Ta), gm>0
            float pv  = Pl * vi;
            float t1  = pv - E * ge;
            float G1  = fmaxf((H1 + Sm) + t1, 0.0f);
            float t2  = (Pl - pv) - gl;
            float G0  = fmaxf((H0 + t2) + G1, 0.0f);
            float m1  = fminf(G1, gl);
            float Q1a = m1 * k1;
            float G2  = fmaf(Q1a, kb, H2);
            yv[b] = fmaf(G0, c0, fmaf(m1, c1, G2 * c2));
            S0 = S - Sm;
            H0 = G0 * k0c;
            H1 = fminf(G1 - Q1a, gl);
            H2 = G2 * k2c;
        }

        // batched butterfly: 8 independent 6-level chains -> latency hidden
#pragma unroll
        for (int off = 32; off; off >>= 1) {
#pragma unroll
            for (int b = 0; b < 8; b++) yv[b] += __shfl_xor(yv[b], off);
        }

        if (lane == 0) {
#pragma unroll
            for (int b = 0; b < 8; b++) {
                int t = t0 + b;
                if (t < NT) Y[(size_t)t * NS + s] = yv[b] + qb;
            }
        }
    }
}

extern "C" void kernel_launch(void* const* d_in, const int* in_sizes, int n_in,
                              void* d_out, int out_size, void* d_ws, size_t ws_size,
                              hipStream_t stream) {
    const float* x  = (const float*)d_in[0];   // [NT, NS, 4]
    const float* xc = (const float*)d_in[1];   // [NS, NG]
    const float* Wm = (const float*)d_in[2];   // [NW, NG]
    const float* bv = (const float*)d_in[3];   // [NW]
    float* out = (float*)d_out;                // [NT, NS] fp32

    float* wbuf = (float*)d_ws;                                 // NS*WSTR floats
    size_t wbytes = (size_t)NS * WSTR * sizeof(float);          // 4,259,840 B
    float* fbuf = (float*)((char*)d_ws + wbytes);               // NT*NS float4
    size_t need = wbytes + (size_t)NT * NS * 4 * sizeof(float); // ~16.2 MB

    gemm_kernel<<<dim3(32, 8), 256, 0, stream>>>(xc, Wm, bv, wbuf);

    if (ws_size >= need) {
        forcing_kernel<<<(NT * NS + 255) / 256, 256, 0, stream>>>(x, fbuf, NT * NS);
        scan_kernel<true><<<NS / 4, 256, 0, stream>>>(fbuf, wbuf, out);
    } else {
        scan_kernel<false><<<NS / 4, 256, 0, stream>>>(x, wbuf, out);
    }
}

// Round 4
// 121.843 us; speedup vs baseline: 1.8309x; 1.3443x over previous
//
#include <hip/hip_runtime.h>
#include <math.h>

#define NT 365
#define NS 2048
#define NH 64
#define NG 128
#define NW 513      // nh*8+1
#define WSTR 520    // padded row stride for w buffer

__device__ __forceinline__ float sigmoidf_(float x) {
    return 1.0f / (1.0f + __expf(-x));
}

// ---------------- Kernel A: forcing transform (Ps, Pl, E, relu(Ta)) ----------
__global__ __launch_bounds__(256) void forcing_kernel(const float* __restrict__ x,
                                                      float* __restrict__ f, int n) {
    int i = blockIdx.x * blockDim.x + threadIdx.x;
    if (i >= n) return;
    float4 v = ((const float4*)x)[i];
    float P = v.x, E = v.y, T1 = v.z, T2 = v.w;
    float Ta = 0.5f * (T1 + T2);
    float rP;
    if (T2 <= 0.0f)       rP = 0.0f;                 // mask0 wins (applied last in ref)
    else if (T1 >= 0.0f)  rP = 1.0f;
    else                  rP = 1.0f - acosf((T1 + T2) / (T2 - T1)) * (1.0f / 3.1415f);
    float Ps = (1.0f - rP) * P;
    float Pl = rP * P;
    ((float4*)f)[i] = make_float4(Ps, Pl, E, fmaxf(Ta, 0.0f));  // store relu(Ta)
}

// ---------------- Kernel B: w = xc @ W^T + b  -> [NS, NW] (stride WSTR) ------
// 64(s) x 64(j) tile, K=128 staged in LDS, 4x4 register block.
// j-tile 2 (cols 128..191) is never consumed by the scan -> skipped via remap.
__global__ __launch_bounds__(256) void gemm_kernel(const float* __restrict__ xc,
                                                   const float* __restrict__ Wm,
                                                   const float* __restrict__ bv,
                                                   float* __restrict__ w) {
    __shared__ float xcs[64][132];  // +4 pad: breaks bank conflict on column reads
    __shared__ float Wsh[64][132];
    const int sTile = blockIdx.x * 64;                       // 32 tiles
    const int by = blockIdx.y;
    const int jt = (by >= 2) ? by + 1 : by;                  // skip unused tile 2
    const int jTile = jt * 64;
    const int t = threadIdx.x;

    for (int i = 0; i < 8; i++) {
        int f4  = t + i * 256;
        int row = f4 >> 5;
        int c4  = (f4 & 31) * 4;
        float4 v = ((const float4*)(xc + (size_t)(sTile + row) * NG))[f4 & 31];
        xcs[row][c4] = v.x; xcs[row][c4 + 1] = v.y; xcs[row][c4 + 2] = v.z; xcs[row][c4 + 3] = v.w;
        int jr = jTile + row;
        float4 wv = make_float4(0.f, 0.f, 0.f, 0.f);
        if (jr < NW) wv = ((const float4*)(Wm + (size_t)jr * NG))[f4 & 31];
        Wsh[row][c4] = wv.x; Wsh[row][c4 + 1] = wv.y; Wsh[row][c4 + 2] = wv.z; Wsh[row][c4 + 3] = wv.w;
    }
    __syncthreads();

    const int tx = t & 15, ty = t >> 4;
    float acc[4][4] = {};
#pragma unroll 4
    for (int k = 0; k < 128; k++) {
        float a0 = xcs[ty][k], a1 = xcs[ty + 16][k], a2 = xcs[ty + 32][k], a3 = xcs[ty + 48][k];
        float b0 = Wsh[tx][k], b1 = Wsh[tx + 16][k], b2 = Wsh[tx + 32][k], b3 = Wsh[tx + 48][k];
        acc[0][0] += a0 * b0; acc[0][1] += a0 * b1; acc[0][2] += a0 * b2; acc[0][3] += a0 * b3;
        acc[1][0] += a1 * b0; acc[1][1] += a1 * b1; acc[1][2] += a1 * b2; acc[1][3] += a1 * b3;
        acc[2][0] += a2 * b0; acc[2][1] += a2 * b1; acc[2][2] += a2 * b2; acc[2][3] += a2 * b3;
        acc[3][0] += a3 * b0; acc[3][1] += a3 * b1; acc[3][2] += a3 * b2; acc[3][3] += a3 * b3;
    }
#pragma unroll
    for (int i = 0; i < 4; i++) {
        int s = sTile + ty + 16 * i;
#pragma unroll
        for (int j = 0; j < 4; j++) {
            int jj = jTile + tx + 16 * j;
            if (jj < NW) w[(size_t)s * WSTR + jj] = acc[i][j] + bv[jj];
        }
    }
}

// ---------------- Kernel C: sequential scan, one wave per site ----------------
// Per step: one ds_write_b32 into a per-wave [h][t] tile (stride 33 -> 2-way
// banks, free). Every 32 steps the wave transposes: lane tau sums column
// (tau&31) over 32 h-values with immediate-offset ds_read_b32 (zero addr
// math), one shfl_xor(32) combines the two h-halves, one predicated store.
template <bool PRE>
__global__ __launch_bounds__(256) void scan_kernel(const float* __restrict__ fx,
                                                   const float* __restrict__ w,
                                                   float* __restrict__ Y) {
    __shared__ float ybuf[4][64][33];   // 33,792 B per block (4 waves)
    const int wave = threadIdx.x >> 6;
    const int lane = threadIdx.x & 63;
    const int s = blockIdx.x * 4 + wave;
    const float* wr = w + (size_t)s * WSTR;

    // gate parameters (per lane = per hidden unit)
    float gm = __expf(wr[lane]) + 1.0f;            // w[:, 0:64]
    float ge = 2.0f * sigmoidf_(wr[64 + lane]);    // w[:, 64:128]
    float k0 = sigmoidf_(wr[192 + lane]);          // w[:, 192:256]
    float w4 = wr[256 + lane];                     // w[:, 256:320]
    float k1 = sigmoidf_(w4);
    float k2 = sigmoidf_(wr[320 + lane]);          // w[:, 320:384]
    float gl = __expf(wr[384 + lane]);             // w[:, 384:448]
    float kb = sigmoidf_(wr[448 + lane]) * 0.1f;   // w[:, 448:512]
    float wl = wr[512];                            // w[:, 512] (per-site scalar)
    float qb = fmaxf(wl, 0.0f) * (1.0f / (float)NH);
    float vi = sigmoidf_(wl);

    // softmax over the 64 lanes of w4 -> ga   (setup cost, once)
    float m = w4;
#pragma unroll
    for (int off = 32; off; off >>= 1) m = fmaxf(m, __shfl_xor(m, off));
    float ex = __expf(w4 - m);
    float sum = ex;
#pragma unroll
    for (int off = 32; off; off >>= 1) sum += __shfl_xor(sum, off);
    float ga = ex / sum;

    // folded coefficients:
    //   y_h = G0*c0 + min(G1,gl)*c1 + G2*c2 ;  Sum_h ga*qb = qb
    //   H0' = G0*(1-k0);  H2' = G2*(1-k2)
    float c0  = k0 * ga;
    float c1  = k1 * (1.0f - kb) * ga;
    float c2  = k2 * ga;
    float k0c = 1.0f - k0;
    float k2c = 1.0f - k2;
    float geN = -ge;            // t1 = fmaf(E, geN, Pl*vi)
    float glN = -gl;            // t2 = fmaf(Pl, viC, glN)
    float viC = 1.0f - vi;

    float S0 = 0.f, H0 = 0.f, H1 = 0.f, H2 = 0.f;

    // wave-uniform forcing pointer (readfirstlane -> SMEM-eligible loads)
    const int su = __builtin_amdgcn_readfirstlane(s);
    const float4* fp = (const float4*)fx + su;

    float* wp = &ybuf[wave][lane][0];                    // write: row h=lane
    const float* rp = &ybuf[wave][(lane >> 5) << 5][lane & 31];  // read: col

    float4 vbuf[8];
#pragma unroll
    for (int b = 0; b < 8; b++) vbuf[b] = fp[b * NS];

    for (int sb = 0; sb < 12; sb++) {                    // 12*32 = 384 >= NT
        const int t0 = sb * 32;
        for (int ib = 0; ib < 4; ib++) {
#pragma unroll
            for (int b = 0; b < 8; b++) {
                const int tl = ib * 8 + b;
                float4 v = vbuf[b];
                int tn = t0 + (ib + 1) * 8 + b;          // prefetch (clamped)
                tn = tn < NT ? tn : NT - 1;
                vbuf[b] = fp[(size_t)tn * NS];

                float Ps, Pl, E, TaR;
                if (PRE) {
                    Ps = v.x; Pl = v.y; E = v.z; TaR = v.w;
                } else {
                    float P = v.x; E = v.y;
                    float T1 = v.z, T2 = v.w;
                    float Ta = 0.5f * (T1 + T2);
                    float rP;
                    if (T2 <= 0.0f)      rP = 0.0f;
                    else if (T1 >= 0.0f) rP = 1.0f;
                    else                 rP = 1.0f - acosf((T1 + T2) / (T2 - T1)) * (1.0f / 3.1415f);
                    Ps = (1.0f - rP) * P;
                    Pl = rP * P;
                    TaR = fmaxf(Ta, 0.0f);
                }
                float S   = S0 + Ps;
                float Sm  = fminf(S0, gm * TaR);         // relu(Ta*gm)=gm*relu(Ta)
                S0 = S - Sm;
                float G1  = fmaxf(H1 + Sm + fmaf(E, geN, Pl * vi), 0.0f);
                float G0  = fmaxf(H0 + G1 + fmaf(Pl, viC, glN), 0.0f);
                float m1  = fminf(G1, gl);
                float Q1a = m1 * k1;
                float G2  = fmaf(Q1a, kb, H2);
                wp[tl] = fmaf(G0, c0, fmaf(m1, c1, G2 * c2));
                H0 = G0 * k0c;
                H1 = fminf(G1 - Q1a, gl);
                H2 = G2 * k2c;
            }
        }
        // transpose-reduce: lane tau sums 32 h-values of column (tau&31)
        float a0 = 0.f, a1 = 0.f, a2 = 0.f, a3 = 0.f;
#pragma unroll
        for (int j = 0; j < 32; j += 4) {
            a0 += rp[(size_t)j * 33];
            a1 += rp[(size_t)(j + 1) * 33];
            a2 += rp[(size_t)(j + 2) * 33];
            a3 += rp[(size_t)(j + 3) * 33];
        }
        float part = (a0 + a1) + (a2 + a3);
        float full = part + __shfl_xor(part, 32);        // combine h-halves
        int t = t0 + lane;                               // lanes 0..31 valid
        if (lane < 32 && t < NT) Y[(size_t)t * NS + s] = full + qb;
    }
}

extern "C" void kernel_launch(void* const* d_in, const int* in_sizes, int n_in,
                              void* d_out, int out_size, void* d_ws, size_t ws_size,
                              hipStream_t stream) {
    const float* x  = (const float*)d_in[0];   // [NT, NS, 4]
    const float* xc = (const float*)d_in[1];   // [NS, NG]
    const float* Wm = (const float*)d_in[2];   // [NW, NG]
    const float* bv = (const float*)d_in[3];   // [NW]
    float* out = (float*)d_out;                // [NT, NS] fp32

    float* wbuf = (float*)d_ws;                                 // NS*WSTR floats
    size_t wbytes = (size_t)NS * WSTR * sizeof(float);          // 4,259,840 B
    float* fbuf = (float*)((char*)d_ws + wbytes);               // NT*NS float4
    size_t need = wbytes + (size_t)NT * NS * 4 * sizeof(float); // ~16.2 MB

    gemm_kernel<<<dim3(32, 8), 256, 0, stream>>>(xc, Wm, bv, wbuf);

    if (ws_size >= need) {
        forcing_kernel<<<(NT * NS + 255) / 256, 256, 0, stream>>>(x, fbuf, NT * NS);
        scan_kernel<true><<<NS / 4, 256, 0, stream>>>(fbuf, wbuf, out);
    } else {
        scan_kernel<false><<<NS / 4, 256, 0, stream>>>(x, wbuf, out);
    }
}